// Round 1
// baseline (310.424 us; speedup 1.0000x reference)
//
#include <hip/hip_runtime.h>

// PseudoImageScatter: img[f, y, x] = pillar_features[p, f], last pillar wins
// on duplicate (y,x). Gather formulation:
//   pass 1: winner[y*W+x] = atomicMax over pillar indices  (last-wins == max idx)
//   pass 2: every output element written exactly once, coalesced float4 stores.

constexpr int H  = 1024;
constexpr int W  = 1024;
constexpr int HW = H * W;
constexpr int NF = 64;

__global__ void winner_kernel(const int* __restrict__ coords,
                              int* __restrict__ winner, int np) {
    int p = blockIdx.x * blockDim.x + threadIdx.x;
    if (p >= np) return;
    int y = coords[p * 3 + 1];
    int x = coords[p * 3 + 2];
    if ((unsigned)x < (unsigned)W && (unsigned)y < (unsigned)H) {
        atomicMax(winner + (y * W + x), p);   // device-scope, cross-XCD safe
    }
}

// One thread per 4 cells -> 16 B/lane stores (1 KiB per wave per instr).
// Empty cells (winner < 0) write zeros; their predicated loads hit row 0
// (broadcast, L1-resident) so they cost ~nothing.
__global__ void __launch_bounds__(256) fill_kernel(const float* __restrict__ feat,
                                                   const int* __restrict__ winner,
                                                   float* __restrict__ out) {
    int g    = blockIdx.x * blockDim.x + threadIdx.x;  // cell-group of 4
    int cell = g * 4;

    int4 w = *(const int4*)(winner + cell);
    const float* r0 = feat + (size_t)max(w.x, 0) * NF;
    const float* r1 = feat + (size_t)max(w.y, 0) * NF;
    const float* r2 = feat + (size_t)max(w.z, 0) * NF;
    const float* r3 = feat + (size_t)max(w.w, 0) * NF;
    bool v0 = w.x >= 0, v1 = w.y >= 0, v2 = w.z >= 0, v3 = w.w >= 0;

    float* o = out + cell;
#pragma unroll 4
    for (int f = 0; f < NF; ++f) {
        float4 v;
        v.x = v0 ? r0[f] : 0.0f;
        v.y = v1 ? r1[f] : 0.0f;
        v.z = v2 ? r2[f] : 0.0f;
        v.w = v3 ? r3[f] : 0.0f;
        *(float4*)(o + (size_t)f * HW) = v;
    }
}

extern "C" void kernel_launch(void* const* d_in, const int* in_sizes, int n_in,
                              void* d_out, int out_size, void* d_ws, size_t ws_size,
                              hipStream_t stream) {
    const float* feat   = (const float*)d_in[0];
    const int*   coords = (const int*)d_in[1];   // int64 in ref, delivered as int32
    float*       out    = (float*)d_out;
    int np = in_sizes[1] / 3;                    // 100000

    int* winner = (int*)d_ws;                    // HW ints = 4 MiB scratch

    // winner := -1 everywhere (0xFF bytes). Stream-ordered, graph-capturable.
    hipMemsetAsync(winner, 0xFF, (size_t)HW * sizeof(int), stream);

    winner_kernel<<<(np + 255) / 256, 256, 0, stream>>>(coords, winner, np);

    fill_kernel<<<HW / 4 / 256, 256, 0, stream>>>(feat, winner, out);
}

// Round 2
// 306.913 us; speedup vs baseline: 1.0114x; 1.0114x over previous
//
#include <hip/hip_runtime.h>

// PseudoImageScatter: img[f, y, x] = pillar_features[p, f], last pillar wins.
// Pass 1: winner[y*W+x] = atomicMax(pillar idx)  (last-wins == max idx, np semantics)
// Pass 2: LDS-transpose gather: per 64-cell tile, stage occupied rows into LDS
//         (vectorized float4 row loads), then write all 64 feature planes with
//         coalesced float4 stores. Every output element written exactly once.

constexpr int H  = 1024;
constexpr int W  = 1024;
constexpr int HW = H * W;
constexpr int NF = 64;
constexpr int TILE = 64;            // cells per block
constexpr int LSTR = NF + 1;        // 65-float stride: bank=(c+f)%32 -> 2-way only (free)

__global__ void winner_kernel(const int* __restrict__ coords,
                              int* __restrict__ winner, int np) {
    int p = blockIdx.x * blockDim.x + threadIdx.x;
    if (p >= np) return;
    int y = coords[p * 3 + 1];
    int x = coords[p * 3 + 2];
    if ((unsigned)x < (unsigned)W && (unsigned)y < (unsigned)H) {
        atomicMax(winner + (y * W + x), p);   // device-scope, cross-XCD safe
    }
}

__global__ void __launch_bounds__(256) fill_kernel(const float* __restrict__ feat,
                                                   const int* __restrict__ winner,
                                                   float* __restrict__ out) {
    __shared__ float lds[TILE * LSTR];
    __shared__ int   wc[TILE];

    const int base = blockIdx.x * TILE;   // first cell of this tile
    const int t    = threadIdx.x;

    if (t < TILE) wc[t] = winner[base + t];
    __syncthreads();

    // ---- Phase A: stage rows. 4 threads per cell; thread j covers 16 floats.
    {
        const int c  = t >> 2;            // cell within tile, 0..63
        const int j  = t & 3;             // quarter-row, 0..3
        const int wp = wc[c];
        float* dst = lds + c * LSTR + j * 16;
        if (wp >= 0) {
            const float4* row = (const float4*)(feat + (size_t)wp * NF) + j * 4;
            float4 a = row[0], b = row[1], cc = row[2], d = row[3];
            // stride 65 breaks 16B alignment -> scalar LDS writes (conflict-free)
            dst[0]=a.x; dst[1]=a.y; dst[2]=a.z; dst[3]=a.w;
            dst[4]=b.x; dst[5]=b.y; dst[6]=b.z; dst[7]=b.w;
            dst[8]=cc.x; dst[9]=cc.y; dst[10]=cc.z; dst[11]=cc.w;
            dst[12]=d.x; dst[13]=d.y; dst[14]=d.z; dst[15]=d.w;
        } else {
#pragma unroll
            for (int k = 0; k < 16; ++k) dst[k] = 0.0f;
        }
    }
    __syncthreads();

    // ---- Phase B: coalesced output. Thread (f0,cg) writes float4 = 4 cells of
    // plane f; 16 lanes cover a contiguous 256B segment per plane.
    {
        const int f0 = t >> 4;            // 0..15
        const int cg = t & 15;            // 0..15 -> cells cg*4..cg*4+3
#pragma unroll
        for (int iter = 0; iter < 4; ++iter) {
            const int f = iter * 16 + f0;
            float4 v;
            v.x = lds[(cg * 4 + 0) * LSTR + f];
            v.y = lds[(cg * 4 + 1) * LSTR + f];
            v.z = lds[(cg * 4 + 2) * LSTR + f];
            v.w = lds[(cg * 4 + 3) * LSTR + f];
            *(float4*)(out + (size_t)f * HW + base + cg * 4) = v;
        }
    }
}

extern "C" void kernel_launch(void* const* d_in, const int* in_sizes, int n_in,
                              void* d_out, int out_size, void* d_ws, size_t ws_size,
                              hipStream_t stream) {
    const float* feat   = (const float*)d_in[0];
    const int*   coords = (const int*)d_in[1];
    float*       out    = (float*)d_out;
    int np = in_sizes[1] / 3;

    int* winner = (int*)d_ws;   // HW ints = 4 MiB scratch

    hipMemsetAsync(winner, 0xFF, (size_t)HW * sizeof(int), stream);  // winner := -1
    winner_kernel<<<(np + 255) / 256, 256, 0, stream>>>(coords, winner, np);
    fill_kernel<<<HW / TILE, 256, 0, stream>>>(feat, winner, out);
}

// Round 4
// 297.949 us; speedup vs baseline: 1.0419x; 1.0301x over previous
//
#include <hip/hip_runtime.h>

// PseudoImageScatter: img[f, y, x] = pillar_features[p, f], last pillar wins.
// Pass 1: winner[y*W+x] = atomicMax(pillar idx)  (last-wins == max idx)
// Pass 2: 256-cell tiles, feature-major LDS transpose, two f-halves of 32.
//   Phase A: 1 thread/cell, 128B half-row load (8x float4), scalar LDS writes
//            lds[f*256+c] (bank=c%32, 2-way = free).
//   Phase B: per wave, ds_read_b128 conflict-free + 1 KiB contiguous
//            nontemporal store per plane per wave instruction.

constexpr int H    = 1024;
constexpr int W    = 1024;
constexpr int HW   = H * W;
constexpr int NF   = 64;
constexpr int TILE = 256;           // cells per block
constexpr int HALF = 32;            // features per LDS pass

typedef float nt4 __attribute__((ext_vector_type(4)));  // native vec for nontemporal

__global__ void winner_kernel(const int* __restrict__ coords,
                              int* __restrict__ winner, int np) {
    int p = blockIdx.x * blockDim.x + threadIdx.x;
    if (p >= np) return;
    int y = coords[p * 3 + 1];
    int x = coords[p * 3 + 2];
    if ((unsigned)x < (unsigned)W && (unsigned)y < (unsigned)H) {
        atomicMax(winner + (y * W + x), p);   // device-scope, cross-XCD safe
    }
}

__global__ void __launch_bounds__(256) fill_kernel(const float* __restrict__ feat,
                                                   const int* __restrict__ winner,
                                                   float* __restrict__ out) {
    __shared__ float lds[HALF * TILE];        // 32 KiB -> 4 blocks/CU

    const int base = blockIdx.x * TILE;
    const int t    = threadIdx.x;             // == cell within tile for phase A
    const int wp   = winner[base + t];        // coalesced
    const int wv   = t >> 6;                  // wave id 0..3
    const int l    = t & 63;                  // lane

    const float4* row = (const float4*)(feat + (size_t)max(wp, 0) * NF);

#pragma unroll
    for (int h = 0; h < 2; ++h) {
        // ---- Phase A: stage 32 features of this thread's cell, f-major.
        if (wp >= 0) {
#pragma unroll
            for (int j = 0; j < 8; ++j) {
                float4 r = row[h * 8 + j];
                lds[(j * 4 + 0) * TILE + t] = r.x;
                lds[(j * 4 + 1) * TILE + t] = r.y;
                lds[(j * 4 + 2) * TILE + t] = r.z;
                lds[(j * 4 + 3) * TILE + t] = r.w;
            }
        } else {
#pragma unroll
            for (int j = 0; j < HALF; ++j) lds[j * TILE + t] = 0.0f;
        }
        __syncthreads();

        // ---- Phase B: wave wv writes plane f = h*32 + p*4 + wv,
        // cells base..base+255: 64 lanes x 16 B = 1 KiB contiguous / instr.
#pragma unroll
        for (int p = 0; p < 8; ++p) {
            const int floc = p * 4 + wv;
            nt4 v = *(const nt4*)&lds[floc * TILE + l * 4];
            __builtin_nontemporal_store(
                v, (nt4*)(out + (size_t)(h * HALF + floc) * HW + base + l * 4));
        }
        __syncthreads();                      // before next half reuses LDS
    }
}

extern "C" void kernel_launch(void* const* d_in, const int* in_sizes, int n_in,
                              void* d_out, int out_size, void* d_ws, size_t ws_size,
                              hipStream_t stream) {
    const float* feat   = (const float*)d_in[0];
    const int*   coords = (const int*)d_in[1];
    float*       out    = (float*)d_out;
    int np = in_sizes[1] / 3;

    int* winner = (int*)d_ws;   // HW ints = 4 MiB scratch

    (void)hipMemsetAsync(winner, 0xFF, (size_t)HW * sizeof(int), stream);  // winner := -1
    winner_kernel<<<(np + 255) / 256, 256, 0, stream>>>(coords, winner, np);
    fill_kernel<<<HW / TILE, 256, 0, stream>>>(feat, winner, out);
}